// Round 1
// baseline (700.972 us; speedup 1.0000x reference)
//
#include <hip/hip_runtime.h>
#include <math.h>

// Problem constants (fixed by the reference).
#define DDIM   64
#define NPTS   200000
#define NQ     512
#define KSEL   16
#define NLAB   10

// Tiling.
#define TQ     64                        // queries per block
#define TP     128                       // train points per LDS tile
#define CHUNK  2048                      // train points per block
#define NTILES (CHUNK / TP)              // 16
#define NCHUNK ((NPTS + CHUNK - 1) / CHUNK)  // 98
#define QTILES (NQ / TQ)                 // 8

// Fully-unrolled, static-index insertion into a sorted ascending top-16 list.
// Caller guarantees dv < bd[15]. Strict < keeps earlier-inserted (lower index)
// entries ranked above on exact ties, matching top_k tie-break.
__device__ __forceinline__ void insert16(float dv, int gi, float bd[KSEL], int bi[KSEL]) {
    float pd = 0.f; int pi = 0; bool pc = false;
#pragma unroll
    for (int s = 0; s < KSEL; ++s) {
        bool c   = dv < bd[s];
        float nd = c ? (pc ? pd : dv) : bd[s];
        int   ni = c ? (pc ? pi : gi) : bi[s];
        pd = bd[s]; pi = bi[s]; pc = c;
        bd[s] = nd; bi[s] = ni;
    }
}

__global__ __launch_bounds__(256) void knn_chunk_topk(
    const float* __restrict__ X, const float* __restrict__ T,
    float* __restrict__ wsD, int* __restrict__ wsI)
{
    __shared__ __align__(16) float XsT[DDIM * TQ];   // [d][q], stride 64
    __shared__ float x2s[TQ];
    __shared__ __align__(16) float buf[TP * 65];     // TsT[d][p] stride 128 | Ds[p][q] stride 65 | cand
    __shared__ float t2s[TP];

    const int t      = threadIdx.x;
    const int chunk  = blockIdx.x;
    const int qt     = blockIdx.y;
    const int qbase  = qt * TQ;
    const int pchunk = chunk * CHUNK;

    // Stage X^T (coalesced global read; one-time LDS write conflicts are negligible).
    for (int i = t; i < TQ * DDIM; i += 256) {
        int q = i >> 6, d = i & 63;
        XsT[d * TQ + q] = X[(qbase + q) * DDIM + d];
    }
    __syncthreads();
    if (t < TQ) {
        float s = 0.f;
        for (int d = 0; d < DDIM; ++d) { float v = XsT[d * TQ + t]; s += v * v; }
        x2s[t] = s;
    }

    const int cq = (t & 15) * 4;   // 4 queries owned (compute phase)
    const int cp = (t >> 4) * 8;   // 8 points owned (compute phase)
    const int sq = t & 63;         // query owned (scan phase)
    const int sg = t >> 6;         // scan group (0..3)

    float bd[KSEL]; int bi[KSEL];
#pragma unroll
    for (int s = 0; s < KSEL; ++s) { bd[s] = INFINITY; bi[s] = 0x7fffffff; }

    for (int tile = 0; tile < NTILES; ++tile) {
        const int pbase = pchunk + tile * TP;
        __syncthreads();   // previous scan / x2s done before overwriting buf
        // Stage T^T: coalesced float4 global reads, scalar LDS writes.
        for (int i = t; i < TP * DDIM / 4; i += 256) {
            int p  = i >> 4;
            int d4 = (i & 15) * 4;
            int gp = pbase + p;
            float4 v = (gp < NPTS) ? *(const float4*)&T[(size_t)gp * DDIM + d4]
                                   : make_float4(0.f, 0.f, 0.f, 0.f);
            buf[(d4 + 0) * TP + p] = v.x;
            buf[(d4 + 1) * TP + p] = v.y;
            buf[(d4 + 2) * TP + p] = v.z;
            buf[(d4 + 3) * TP + p] = v.w;
        }
        __syncthreads();
        if (t < TP) {
            int gp = pbase + t;
            float s = 0.f;
            for (int d = 0; d < DDIM; ++d) { float v = buf[d * TP + t]; s += v * v; }
            t2s[t] = (gp < NPTS) ? s : INFINITY;
        }
        // Dot products: 4 queries x 8 points per thread, all-b128 conflict-free LDS reads.
        float acc[4][8];
#pragma unroll
        for (int i = 0; i < 4; ++i)
#pragma unroll
            for (int j = 0; j < 8; ++j) acc[i][j] = 0.f;

#pragma unroll 4
        for (int d = 0; d < DDIM; ++d) {
            float4 xv = *(const float4*)&XsT[d * TQ + cq];
            float4 t0 = *(const float4*)&buf[d * TP + cp];
            float4 t1 = *(const float4*)&buf[d * TP + cp + 4];
            float xs[4] = {xv.x, xv.y, xv.z, xv.w};
            float ts[8] = {t0.x, t0.y, t0.z, t0.w, t1.x, t1.y, t1.z, t1.w};
#pragma unroll
            for (int i = 0; i < 4; ++i)
#pragma unroll
                for (int j = 0; j < 8; ++j)
                    acc[i][j] = fmaf(xs[i], ts[j], acc[i][j]);
        }
        __syncthreads();   // everyone done reading buf; t2s visible
        // d2 = x2 + t2 - 2*dot  -> Ds[p][q] (stride 65) in buf
#pragma unroll
        for (int j = 0; j < 8; ++j) {
            float tt = t2s[cp + j];
#pragma unroll
            for (int i = 0; i < 4; ++i) {
                float d2 = x2s[cq + i] + tt - 2.f * acc[i][j];
                buf[(cp + j) * 65 + (cq + i)] = d2;
            }
        }
        __syncthreads();
        // Scan: each thread handles 32 points of its query, private top-16.
#pragma unroll 1
        for (int j = 0; j < 32; ++j) {
            int p    = sg * 32 + j;
            float dv = buf[p * 65 + sq];
            int gidx = pbase + p;
            if (gidx < NPTS && dv < bd[KSEL - 1])
                insert16(dv, gidx, bd, bi);
        }
    }
    __syncthreads();
    // Dump 4 partial lists per query into LDS (stride 65 rows: conflict-free).
    {
        float* candD = buf;
        int*   candI = (int*)(buf + TQ * 65);
#pragma unroll
        for (int s = 0; s < KSEL; ++s) {
            candD[sq * 65 + sg * KSEL + s] = bd[s];
            candI[sq * 65 + sg * KSEL + s] = bi[s];
        }
    }
    __syncthreads();
    // Per-query merge of 64 candidates -> chunk top-16 -> workspace.
    if (t < TQ) {
        const float* candD = buf;
        const int*   candI = (const int*)(buf + TQ * 65);
        float fd[KSEL]; int fi[KSEL];
#pragma unroll
        for (int s = 0; s < KSEL; ++s) { fd[s] = INFINITY; fi[s] = 0x7fffffff; }
#pragma unroll 1
        for (int j = 0; j < 4 * KSEL; ++j) {
            float dv = candD[t * 65 + j];
            int   gi = candI[t * 65 + j];
            if (dv < fd[KSEL - 1]) insert16(dv, gi, fd, fi);
        }
        size_t base = ((size_t)(qbase + t) * NCHUNK + chunk) * KSEL;
#pragma unroll
        for (int s = 0; s < KSEL; ++s) { wsD[base + s] = fd[s]; wsI[base + s] = fi[s]; }
    }
}

__global__ __launch_bounds__(64) void knn_vote(
    const float* __restrict__ wsD, const int* __restrict__ wsI,
    const int* __restrict__ labels, int* __restrict__ out)
{
    const int q = blockIdx.x;
    const int t = threadIdx.x;
    const int M = NCHUNK * KSEL;   // 1568 candidates per query

    float bd[KSEL]; int bi[KSEL];
#pragma unroll
    for (int s = 0; s < KSEL; ++s) { bd[s] = INFINITY; bi[s] = 0x7fffffff; }

    const float* rd = wsD + (size_t)q * M;
    const int*   ri = wsI + (size_t)q * M;
#pragma unroll 1
    for (int j = t; j < M; j += 64) {
        float dv = rd[j];
        if (dv < bd[KSEL - 1]) insert16(dv, ri[j], bd, bi);
    }

    __shared__ float sD[64 * 17];
    __shared__ int   sI[64 * 17];
#pragma unroll
    for (int s = 0; s < KSEL; ++s) { sD[t * 17 + s] = bd[s]; sI[t * 17 + s] = bi[s]; }
    __syncthreads();

    if (t == 0) {
        float fd[KSEL]; int fi[KSEL];
#pragma unroll
        for (int s = 0; s < KSEL; ++s) { fd[s] = INFINITY; fi[s] = 0x7fffffff; }
#pragma unroll 1
        for (int j = 0; j < 64; ++j) {
#pragma unroll 1
            for (int s = 0; s < KSEL; ++s) {
                float dv = sD[j * 17 + s];
                if (!(dv < fd[KSEL - 1])) break;   // sub-lists sorted ascending
                insert16(dv, sI[j * 17 + s], fd, fi);
            }
        }
        // Weighted vote (inverse distance, zero-distance correction), first-index argmax.
        bool anyz = false;
#pragma unroll
        for (int s = 0; s < KSEL; ++s) {
            float dk = sqrtf(fmaxf(fd[s], 0.f));
            if (dk == 0.f) anyz = true;
        }
        float votes[NLAB];
        for (int l = 0; l < NLAB; ++l) votes[l] = 0.f;
        for (int s = 0; s < KSEL; ++s) {
            float dk = sqrtf(fmaxf(fd[s], 0.f));
            float w  = anyz ? (dk == 0.f ? 1.f : 0.f) : 1.f / dk;
            votes[labels[fi[s]]] += w;
        }
        int best = 0; float bv = votes[0];
        for (int l = 1; l < NLAB; ++l) {
            if (votes[l] > bv) { bv = votes[l]; best = l; }
        }
        out[q] = best;
    }
}

extern "C" void kernel_launch(void* const* d_in, const int* in_sizes, int n_in,
                              void* d_out, int out_size, void* d_ws, size_t ws_size,
                              hipStream_t stream) {
    const float* X      = (const float*)d_in[0];
    const float* T      = (const float*)d_in[1];
    const int*   labels = (const int*)d_in[2];
    int* out = (int*)d_out;

    float* wsD = (float*)d_ws;
    int*   wsI = (int*)((char*)d_ws + (size_t)NQ * NCHUNK * KSEL * sizeof(float));

    knn_chunk_topk<<<dim3(NCHUNK, QTILES), 256, 0, stream>>>(X, T, wsD, wsI);
    knn_vote<<<NQ, 64, 0, stream>>>(wsD, wsI, labels, out);
}

// Round 2
// 348.827 us; speedup vs baseline: 2.0095x; 2.0095x over previous
//
#include <hip/hip_runtime.h>
#include <math.h>

#define DDIM  64
#define NPTS  200000
#define NQ    512
#define KSEL  16
#define NLAB  10
#define CAP   2048

typedef __attribute__((ext_vector_type(8))) __bf16 bf16x8;
typedef __attribute__((ext_vector_type(4))) __bf16 bf16x4;
typedef __attribute__((ext_vector_type(4))) float  f32x4;

// ws layout (bytes):
//   Tb   @ 0          : 200000*64*2 = 25,600,000   (bf16 train features)
//   Xb   @ 25,600,000 : 512*64*2    = 65,536       (bf16 queries)
//   t2   @ 25,665,536 : 200000*4    = 800,000      (fp32 row norms, exact)
//   gmin @ 26,465,536 : 512*4                       (encoded per-query min key)
//   gcnt @ 26,467,584 : 512*4*4                     (counts vs 4 thresholds)
//   ccnt @ 26,475,776 : 512*4                       (candidate counts)
//   cand @ 26,477,824 : 512*2048*4 = 4,194,304      (candidate train indices)
// total ~30.7 MB

__device__ __forceinline__ bf16x8 load_frag(const __bf16* p) {
    int4 v = *reinterpret_cast<const int4*>(p);
    return __builtin_bit_cast(bf16x8, v);
}
__device__ __forceinline__ unsigned enc_f(float x) {
    unsigned b = __float_as_uint(x);
    return (b & 0x80000000u) ? ~b : (b | 0x80000000u);
}
__device__ __forceinline__ float dec_f(unsigned e) {
    unsigned b = (e & 0x80000000u) ? (e & 0x7FFFFFFFu) : ~e;
    return __uint_as_float(b);
}

// ---------- K0: convert T to bf16, compute exact fp32 row norms ----------
__global__ __launch_bounds__(256) void knn_prep_T(
    const float* __restrict__ Tf, __bf16* __restrict__ Tb, float* __restrict__ t2)
{
    const int t = threadIdx.x;
    const int rowbase = blockIdx.x * 64;
    __shared__ float s[64 * 65];
    const float* src = Tf + (size_t)rowbase * 64;
#pragma unroll
    for (int i = 0; i < 4; ++i) {
        int lin = i * 1024 + t * 4;
        float4 v = *reinterpret_cast<const float4*>(src + lin);
        int r = lin >> 6, d = lin & 63;
        s[r * 65 + d + 0] = v.x;
        s[r * 65 + d + 1] = v.y;
        s[r * 65 + d + 2] = v.z;
        s[r * 65 + d + 3] = v.w;
        bf16x4 bv = {(__bf16)v.x, (__bf16)v.y, (__bf16)v.z, (__bf16)v.w};
        *reinterpret_cast<long long*>(Tb + (size_t)rowbase * 64 + lin) =
            __builtin_bit_cast(long long, bv);
    }
    __syncthreads();
    if (t < 64) {
        float sum = 0.f;
#pragma unroll
        for (int d = 0; d < 64; ++d) { float v = s[t * 65 + d]; sum = fmaf(v, v, sum); }
        t2[rowbase + t] = sum;
    }
}

// ---------- K0x: convert X to bf16, init counters ----------
__global__ __launch_bounds__(256) void knn_prep_X(
    const float* __restrict__ Xf, __bf16* __restrict__ Xb,
    unsigned* __restrict__ gmin, int* __restrict__ gcnt, int* __restrict__ ccnt)
{
    const int g = blockIdx.x * 256 + threadIdx.x;
    if (g < (NQ * DDIM) / 4) {
        float4 v = reinterpret_cast<const float4*>(Xf)[g];
        bf16x4 bv = {(__bf16)v.x, (__bf16)v.y, (__bf16)v.z, (__bf16)v.w};
        *reinterpret_cast<long long*>(Xb + (size_t)g * 4) = __builtin_bit_cast(long long, bv);
    }
    if (g < NQ) gmin[g] = 0xFFFFFFFFu;
    if (g < NQ * 4) gcnt[g] = 0;
    if (g < NQ) ccnt[g] = 0;
}

// ---------- K1: per-query min of key = t2 - 2*dot (bf16 MFMA) ----------
__global__ __launch_bounds__(256) void knn_pass_min(
    const __bf16* __restrict__ Tb, const __bf16* __restrict__ Xb,
    const float* __restrict__ t2, unsigned* __restrict__ gmin)
{
    const int t = threadIdx.x;
    const int lane = t & 63, w = t >> 6;
    const int qg = blockIdx.y;
    const int pbase = blockIdx.x * 1024 + w * 256;
    const int lrow = lane & 15, lk = lane >> 4;

    bf16x8 bfrag[4][2];
#pragma unroll
    for (int qt = 0; qt < 4; ++qt)
#pragma unroll
        for (int kb = 0; kb < 2; ++kb)
            bfrag[qt][kb] = load_frag(Xb + (size_t)(qg*64 + qt*16 + lrow)*64 + kb*32 + lk*8);

    float vmin[4] = {INFINITY, INFINITY, INFINITY, INFINITY};

    for (int it = 0; it < 16; ++it) {
        int p0 = pbase + it * 16;
        if (p0 >= NPTS) break;
        bf16x8 a0 = load_frag(Tb + (size_t)(p0 + lrow)*64 + 0  + lk*8);
        bf16x8 a1 = load_frag(Tb + (size_t)(p0 + lrow)*64 + 32 + lk*8);
        float4 t2v = *reinterpret_cast<const float4*>(t2 + p0 + lk*4);
        const float tt[4] = {t2v.x, t2v.y, t2v.z, t2v.w};
        f32x4 acc[4];
#pragma unroll
        for (int qt = 0; qt < 4; ++qt) {
            f32x4 z = {0.f, 0.f, 0.f, 0.f};
            acc[qt] = __builtin_amdgcn_mfma_f32_16x16x32_bf16(a0, bfrag[qt][0], z, 0, 0, 0);
            acc[qt] = __builtin_amdgcn_mfma_f32_16x16x32_bf16(a1, bfrag[qt][1], acc[qt], 0, 0, 0);
        }
#pragma unroll
        for (int qt = 0; qt < 4; ++qt)
#pragma unroll
            for (int r = 0; r < 4; ++r) {
                float key = fmaf(-2.f, acc[qt][r], tt[r]);
                vmin[qt] = fminf(vmin[qt], key);
            }
    }
#pragma unroll
    for (int qt = 0; qt < 4; ++qt) {
        vmin[qt] = fminf(vmin[qt], __shfl_xor(vmin[qt], 16));
        vmin[qt] = fminf(vmin[qt], __shfl_xor(vmin[qt], 32));
    }
    __shared__ float sm[4][64];
    if (lane < 16)
#pragma unroll
        for (int qt = 0; qt < 4; ++qt) sm[w][qt*16 + lane] = vmin[qt];
    __syncthreads();
    if (t < 64) {
        float m = fminf(fminf(sm[0][t], sm[1][t]), fminf(sm[2][t], sm[3][t]));
        atomicMin(&gmin[qg*64 + t], enc_f(m));
    }
}

// ---------- K2: count keys below min + {7,15,31,63} ----------
__global__ __launch_bounds__(256) void knn_pass_count(
    const __bf16* __restrict__ Tb, const __bf16* __restrict__ Xb,
    const float* __restrict__ t2, const unsigned* __restrict__ gmin,
    int* __restrict__ gcnt)
{
    const int t = threadIdx.x;
    const int lane = t & 63, w = t >> 6;
    const int qg = blockIdx.y;
    const int pbase = blockIdx.x * 1024 + w * 256;
    const int lrow = lane & 15, lk = lane >> 4;

    bf16x8 bfrag[4][2];
    float m[4];
#pragma unroll
    for (int qt = 0; qt < 4; ++qt) {
#pragma unroll
        for (int kb = 0; kb < 2; ++kb)
            bfrag[qt][kb] = load_frag(Xb + (size_t)(qg*64 + qt*16 + lrow)*64 + kb*32 + lk*8);
        m[qt] = dec_f(gmin[qg*64 + qt*16 + lrow]);
    }
    int cnt[4][4] = {};

    for (int it = 0; it < 16; ++it) {
        int p0 = pbase + it * 16;
        if (p0 >= NPTS) break;
        bf16x8 a0 = load_frag(Tb + (size_t)(p0 + lrow)*64 + 0  + lk*8);
        bf16x8 a1 = load_frag(Tb + (size_t)(p0 + lrow)*64 + 32 + lk*8);
        float4 t2v = *reinterpret_cast<const float4*>(t2 + p0 + lk*4);
        const float tt[4] = {t2v.x, t2v.y, t2v.z, t2v.w};
        f32x4 acc[4];
#pragma unroll
        for (int qt = 0; qt < 4; ++qt) {
            f32x4 z = {0.f, 0.f, 0.f, 0.f};
            acc[qt] = __builtin_amdgcn_mfma_f32_16x16x32_bf16(a0, bfrag[qt][0], z, 0, 0, 0);
            acc[qt] = __builtin_amdgcn_mfma_f32_16x16x32_bf16(a1, bfrag[qt][1], acc[qt], 0, 0, 0);
        }
#pragma unroll
        for (int qt = 0; qt < 4; ++qt)
#pragma unroll
            for (int r = 0; r < 4; ++r) {
                float rel = fmaf(-2.f, acc[qt][r], tt[r]) - m[qt];
                cnt[qt][0] += (rel < 7.f);
                cnt[qt][1] += (rel < 15.f);
                cnt[qt][2] += (rel < 31.f);
                cnt[qt][3] += (rel < 63.f);
            }
    }
#pragma unroll
    for (int qt = 0; qt < 4; ++qt)
#pragma unroll
        for (int i = 0; i < 4; ++i) {
            cnt[qt][i] += __shfl_xor(cnt[qt][i], 16);
            cnt[qt][i] += __shfl_xor(cnt[qt][i], 32);
        }
    __shared__ int sc[4][64][4];
    if (lane < 16)
#pragma unroll
        for (int qt = 0; qt < 4; ++qt)
#pragma unroll
            for (int i = 0; i < 4; ++i) sc[w][qt*16 + lane][i] = cnt[qt][i];
    __syncthreads();
    if (t < 64) {
#pragma unroll
        for (int i = 0; i < 4; ++i) {
            int tot = sc[0][t][i] + sc[1][t][i] + sc[2][t][i] + sc[3][t][i];
            atomicAdd(&gcnt[(qg*64 + t)*4 + i], tot);
        }
    }
}

// ---------- K3: filter keys below adaptive tau, collect candidate indices ----------
__global__ __launch_bounds__(256) void knn_pass_filter(
    const __bf16* __restrict__ Tb, const __bf16* __restrict__ Xb,
    const float* __restrict__ t2, const unsigned* __restrict__ gmin,
    const int* __restrict__ gcnt, int* __restrict__ ccnt, int* __restrict__ cand)
{
    const int t = threadIdx.x;
    const int lane = t & 63, w = t >> 6;
    const int qg = blockIdx.y;
    const int pbase = blockIdx.x * 1024 + w * 256;
    const int lrow = lane & 15, lk = lane >> 4;

    bf16x8 bfrag[4][2];
    float tau[4];
#pragma unroll
    for (int qt = 0; qt < 4; ++qt) {
#pragma unroll
        for (int kb = 0; kb < 2; ++kb)
            bfrag[qt][kb] = load_frag(Xb + (size_t)(qg*64 + qt*16 + lrow)*64 + kb*32 + lk*8);
        int q = qg*64 + qt*16 + lrow;
        float m = dec_f(gmin[q]);
        int c0 = gcnt[q*4+0], c1 = gcnt[q*4+1], c2 = gcnt[q*4+2];
        float lim = (c0 >= KSEL) ? 7.f : (c1 >= KSEL) ? 15.f : (c2 >= KSEL) ? 31.f : 63.f;
        tau[qt] = m + lim + 1.0f;   // +1.0 margin covers bf16 approx error both ways
    }
    __shared__ int wbuf[4][256];
    __shared__ int wcnt[4];
    if (t < 4) wcnt[t] = 0;
    __syncthreads();

    for (int it = 0; it < 16; ++it) {
        int p0 = pbase + it * 16;
        if (p0 >= NPTS) break;
        bf16x8 a0 = load_frag(Tb + (size_t)(p0 + lrow)*64 + 0  + lk*8);
        bf16x8 a1 = load_frag(Tb + (size_t)(p0 + lrow)*64 + 32 + lk*8);
        float4 t2v = *reinterpret_cast<const float4*>(t2 + p0 + lk*4);
        const float tt[4] = {t2v.x, t2v.y, t2v.z, t2v.w};
        f32x4 acc[4];
#pragma unroll
        for (int qt = 0; qt < 4; ++qt) {
            f32x4 z = {0.f, 0.f, 0.f, 0.f};
            acc[qt] = __builtin_amdgcn_mfma_f32_16x16x32_bf16(a0, bfrag[qt][0], z, 0, 0, 0);
            acc[qt] = __builtin_amdgcn_mfma_f32_16x16x32_bf16(a1, bfrag[qt][1], acc[qt], 0, 0, 0);
        }
#pragma unroll
        for (int qt = 0; qt < 4; ++qt)
#pragma unroll
            for (int r = 0; r < 4; ++r) {
                float key = fmaf(-2.f, acc[qt][r], tt[r]);
                if (key < tau[qt]) {
                    int pidx = p0 + lk*4 + r;
                    int e = pidx | ((qt*16 + lrow) << 18);
                    int pos = atomicAdd(&wcnt[w], 1);
                    if (pos < 256) wbuf[w][pos] = e;
                    else {  // overflow: append directly
                        int q = qg*64 + qt*16 + lrow;
                        int gp = atomicAdd(&ccnt[q], 1);
                        if (gp < CAP) cand[(size_t)q * CAP + gp] = pidx;
                    }
                }
            }
    }
    __syncthreads();
    int n = min(wcnt[w], 256);
    for (int i = lane; i < n; i += 64) {
        int e = wbuf[w][i];
        int q = qg*64 + (e >> 18);
        int gp = atomicAdd(&ccnt[q], 1);
        if (gp < CAP) cand[(size_t)q * CAP + gp] = e & 0x3FFFF;
    }
}

// ---------- K4: exact fp32 re-rank of candidates + weighted vote ----------
__global__ __launch_bounds__(256) void knn_vote(
    const float* __restrict__ Xf, const float* __restrict__ Tf,
    const float* __restrict__ t2, const int* __restrict__ labels,
    const int* __restrict__ ccnt, const int* __restrict__ cand,
    int* __restrict__ out)
{
    const int q = blockIdx.x;
    const int t = threadIdx.x;
    __shared__ float xrow[64];
    __shared__ unsigned dbits[CAP];
    __shared__ int didx[CAP];
    __shared__ unsigned windb[KSEL];
    __shared__ int winidx[KSEL];

    if (t < 16) {
        float4 v = reinterpret_cast<const float4*>(Xf + (size_t)q * 64)[t];
        xrow[t*4+0] = v.x; xrow[t*4+1] = v.y; xrow[t*4+2] = v.z; xrow[t*4+3] = v.w;
    }
    __syncthreads();
    float x2 = 0.f;
#pragma unroll
    for (int d = 0; d < 64; ++d) x2 = fmaf(xrow[d], xrow[d], x2);

    const int count = min(ccnt[q], CAP);
    for (int c = t; c < count; c += 256) {
        int idx = cand[(size_t)q * CAP + c];
        const float* tr = Tf + (size_t)idx * 64;
        float acc = 0.f;
#pragma unroll
        for (int d4 = 0; d4 < 16; ++d4) {
            float4 v = reinterpret_cast<const float4*>(tr)[d4];
            acc = fmaf(xrow[d4*4+0], v.x, acc);
            acc = fmaf(xrow[d4*4+1], v.y, acc);
            acc = fmaf(xrow[d4*4+2], v.z, acc);
            acc = fmaf(xrow[d4*4+3], v.w, acc);
        }
        float d2 = x2 + t2[idx] - 2.f * acc;
        dbits[c] = __float_as_uint(fmaxf(d2, 0.f));
        didx[c] = idx;
    }
    __syncthreads();

    // 16 rounds of wave-wide lexicographic (dist, train_idx) min-extraction
    for (int round = 0; round < KSEL; ++round) {
        if (t < 64) {
            unsigned long long best = ~0ull; int bpos = -1;
            for (int c = t; c < count; c += 64) {
                unsigned long long k =
                    ((unsigned long long)dbits[c] << 32) | (unsigned)didx[c];
                if (k < best) { best = k; bpos = c; }
            }
            for (int off = 1; off < 64; off <<= 1) {
                unsigned long long ok = __shfl_xor(best, off);
                int op = __shfl_xor(bpos, off);
                if (ok < best) { best = ok; bpos = op; }
            }
            if (t == 0) {
                windb[round] = (unsigned)(best >> 32);
                winidx[round] = (int)(best & 0xFFFFFFFFu);
                if (bpos >= 0) dbits[bpos] = 0xFFFFFFFFu;   // remove winner
            }
        }
        __syncthreads();
    }

    if (t == 0) {
        float dk[KSEL]; int li[KSEL]; bool valid[KSEL];
        bool anyz = false;
#pragma unroll
        for (int s = 0; s < KSEL; ++s) {
            valid[s] = (windb[s] != 0xFFFFFFFFu);
            dk[s] = valid[s] ? sqrtf(__uint_as_float(windb[s])) : INFINITY;
            li[s] = valid[s] ? labels[winidx[s]] : 0;
            if (valid[s] && dk[s] == 0.f) anyz = true;
        }
        float votes[NLAB];
        for (int l = 0; l < NLAB; ++l) votes[l] = 0.f;
#pragma unroll
        for (int s = 0; s < KSEL; ++s) {
            if (!valid[s]) continue;
            float wgt = anyz ? (dk[s] == 0.f ? 1.f : 0.f) : 1.f / dk[s];
            votes[li[s]] += wgt;
        }
        int best = 0; float bv = votes[0];
        for (int l = 1; l < NLAB; ++l)
            if (votes[l] > bv) { bv = votes[l]; best = l; }
        out[q] = best;
    }
}

extern "C" void kernel_launch(void* const* d_in, const int* in_sizes, int n_in,
                              void* d_out, int out_size, void* d_ws, size_t ws_size,
                              hipStream_t stream) {
    const float* Xf     = (const float*)d_in[0];
    const float* Tf     = (const float*)d_in[1];
    const int*   labels = (const int*)d_in[2];
    int* out = (int*)d_out;

    char* wsb = (char*)d_ws;
    __bf16*   Tb   = (__bf16*)(wsb);
    __bf16*   Xb   = (__bf16*)(wsb + 25600000);
    float*    t2   = (float*)(wsb + 25665536);
    unsigned* gmin = (unsigned*)(wsb + 26465536);
    int*      gcnt = (int*)(wsb + 26467584);
    int*      ccnt = (int*)(wsb + 26475776);
    int*      cand = (int*)(wsb + 26477824);

    knn_prep_T<<<NPTS / 64, 256, 0, stream>>>(Tf, Tb, t2);
    knn_prep_X<<<32, 256, 0, stream>>>(Xf, Xb, gmin, gcnt, ccnt);

    dim3 grid((NPTS + 1023) / 1024, NQ / 64);
    knn_pass_min<<<grid, 256, 0, stream>>>(Tb, Xb, t2, gmin);
    knn_pass_count<<<grid, 256, 0, stream>>>(Tb, Xb, t2, gmin, gcnt);
    knn_pass_filter<<<grid, 256, 0, stream>>>(Tb, Xb, t2, gmin, gcnt, ccnt, cand);

    knn_vote<<<NQ, 256, 0, stream>>>(Xf, Tf, t2, labels, ccnt, cand, out);
}